// Round 10
// baseline (225.543 us; speedup 1.0000x reference)
//
#include <hip/hip_runtime.h>
#include <math.h>

// ---------------------------------------------------------------------------
// QCNN forward. Inter-kernel state uses layout F (per batch, 20 bits):
//   F0=a0(u0) F1=a1(t0) F2=a2(s0) F3=a3(t1) F4=a12(u3) F5=a16(u4) F6=a14(s3)
//   F7=a18(s4) F8=a4(u1) F9=a8(u2) F10=a6(s1) F11=a10(s2) F12=a5(t2)
//   F13=a7 F14=a9 F15=a11 F16=a13 F17=a15 F18=a17 F19=a19   (F13..19 = thi)
// pass1: tile=addr bits 0..12, permuted store into F.
// pass2: tile = F bits {0..7,15..19} (in-place safe; gates rescheduled).
// pool:  contiguous 64KB gather per (b,thi); LDS w[t*1120+s*35+u];
//        rho accumulated via global f32 atomics (rho32 zeroed by memset).
// Gate digit r = 2*bit(pa)+bit(pb);  qubit q <-> addr bit 19-q.
// ---------------------------------------------------------------------------

__device__ __forceinline__ float2 cmul(float2 a, float2 b) {
  return make_float2(a.x * b.x - a.y * b.y, a.x * b.y + a.y * b.x);
}
__device__ __forceinline__ float2 cmadd(float2 acc, float2 a, float2 b) {
  acc.x = fmaf(a.x, b.x, fmaf(-a.y, b.y, acc.x));
  acc.y = fmaf(a.x, b.y, fmaf(a.y, b.x, acc.y));
  return acc;
}
// acc += a * conj(b)
__device__ __forceinline__ float2 cmaddc(float2 acc, float2 a, float2 b) {
  acc.x = fmaf(a.x, b.x, fmaf(a.y, b.y, acc.x));
  acc.y = fmaf(a.y, b.x, fmaf(-a.x, b.y, acc.y));
  return acc;
}
__device__ __forceinline__ int pad(int e) { return e + (e >> 4); }
__device__ __forceinline__ int ins(int x, int p) {  // insert zero bit at p
  return ((x >> p) << (p + 1)) | (x & ((1 << p) - 1));
}

__device__ __forceinline__ void gate4(float2& v0, float2& v1, float2& v2, float2& v3,
                                      const float2 (&U)[16]) {
  float2 n0 = cmul(U[0], v0);  n0 = cmadd(n0, U[1], v1);  n0 = cmadd(n0, U[2], v2);  n0 = cmadd(n0, U[3], v3);
  float2 n1 = cmul(U[4], v0);  n1 = cmadd(n1, U[5], v1);  n1 = cmadd(n1, U[6], v2);  n1 = cmadd(n1, U[7], v3);
  float2 n2 = cmul(U[8], v0);  n2 = cmadd(n2, U[9], v1);  n2 = cmadd(n2, U[10], v2); n2 = cmadd(n2, U[11], v3);
  float2 n3 = cmul(U[12], v0); n3 = cmadd(n3, U[13], v1); n3 = cmadd(n3, U[14], v2); n3 = cmadd(n3, U[15], v3);
  v0 = n0; v1 = n1; v2 = n2; v3 = n3;
}

// NG gates on a 16-elem register block: (o1,o0), (o3,o2), [+(o2,o1) if NG==3]
template <int NG>
__device__ __forceinline__ void gate16n(float2 (&v)[16], const float2 (&U)[16]) {
#pragma unroll
  for (int g = 0; g < 4; g++)
    gate4(v[g * 4 + 0], v[g * 4 + 1], v[g * 4 + 2], v[g * 4 + 3], U);
#pragma unroll
  for (int lo = 0; lo < 4; lo++)
    gate4(v[lo], v[lo + 4], v[lo + 8], v[lo + 12], U);
  if (NG == 3) {
#pragma unroll
    for (int b3 = 0; b3 < 2; b3++)
#pragma unroll
      for (int b0 = 0; b0 < 2; b0++) {
        int j = b3 * 8 + b0;
        gate4(v[j], v[j + 2], v[j + 4], v[j + 6], U);
      }
  }
}

// single 2-qubit gate (pa,pb bit positions) over padded 2^13 LDS tile (512 thr)
__device__ __forceinline__ void apply_gate_tile13(float2* t, const float2 (&U)[16],
                                                  int pa, int pb, int tid) {
  int p0 = pa < pb ? pa : pb;
  int p1 = pa < pb ? pb : pa;
  int m0 = (1 << p0) - 1, m1 = (1 << p1) - 1;
  int ia = 1 << pa, ib = 1 << pb;
#pragma unroll
  for (int g = tid; g < 2048; g += 512) {
    int idx = ((g & ~m0) << 1) | (g & m0);
    idx = ((idx & ~m1) << 1) | (idx & m1);
    int e0 = pad(idx), e1 = pad(idx | ib), e2 = pad(idx | ia), e3 = pad(idx | ia | ib);
    float2 v0 = t[e0], v1 = t[e1], v2 = t[e2], v3 = t[e3];
    gate4(v0, v1, v2, v3, U);
    t[e0] = v0; t[e1] = v1; t[e2] = v2; t[e3] = v3;
  }
}

// register phase over a padded 2^13 tile. q0<q1<q2<q3 = sorted bit positions;
// o0..o3 = gate-ordered strides (gates (o1,o0),(o3,o2)[,(o2,o1)]).
// 512 threads -> exactly one 16-group per thread.
template <int NG>
__device__ __forceinline__ void phase4_f(float2* t, const float2 (&U)[16],
                                         int q0, int q1, int q2, int q3,
                                         int o0, int o1, int o2, int o3, int tid) {
  int idx = ins(ins(ins(ins(tid, q0), q1), q2), q3);
  float2 v[16];
#pragma unroll
  for (int j = 0; j < 16; j++) {
    int off = ((j & 1) ? o0 : 0) + ((j & 2) ? o1 : 0) + ((j & 4) ? o2 : 0) + ((j & 8) ? o3 : 0);
    v[j] = t[pad(idx + off)];
  }
  gate16n<NG>(v, U);
#pragma unroll
  for (int j = 0; j < 16; j++) {
    int off = ((j & 1) ? o0 : 0) + ((j & 2) ? o1 : 0) + ((j & 4) ? o2 : 0) + ((j & 8) ? o3 : 0);
    t[pad(idx + off)] = v[j];
  }
}

// pool register phase (stride-35 LDS): removes u-bits {a_lo<a_hi},
// s-bits {c_lo<c_hi}; o0..o3 = gate-ordered flat strides
template <int NG>
__device__ __forceinline__ void phase4_pool(float2* w, const float2 (&U)[16],
                                            int a_lo, int a_hi, int c_lo, int c_hi,
                                            int o0, int o1, int o2, int o3, int tid) {
  int uu = tid & 7, ss = (tid >> 3) & 7, t_lo = tid >> 6;
  int u = ins(ins(uu, a_lo), a_hi);
  int s = ins(ins(ss, c_lo), c_hi);
  int base = t_lo * 1120 + s * 35 + u;
  float2 v[16];
#pragma unroll
  for (int j = 0; j < 16; j++) {
    int off = ((j & 1) ? o0 : 0) + ((j & 2) ? o1 : 0) + ((j & 4) ? o2 : 0) + ((j & 8) ? o3 : 0);
    v[j] = w[base + off];
  }
  gate16n<NG>(v, U);
#pragma unroll
  for (int j = 0; j < 16; j++) {
    int off = ((j & 1) ? o0 : 0) + ((j & 2) ? o1 : 0) + ((j & 4) ? o2 : 0) + ((j & 8) ? o3 : 0);
    w[base + off] = v[j];
  }
}

// pool P3: gates {1,0} then {2,1} on locals [o0=1(u0), o1=35(s0), o2=2(u1)]
__device__ __forceinline__ void pool_p3(float2* w, const float2 (&U)[16], int tid) {
#pragma unroll
  for (int it = 0; it < 2; it++) {
    int h = tid + it * 512;
    int uu = h & 7, ss = (h >> 3) & 15, t_lo = h >> 7;
    int base = t_lo * 1120 + (ss << 1) * 35 + (uu << 2);
    float2 v[8];
    v[0] = w[base];      v[1] = w[base + 1];
    v[4] = w[base + 2];  v[5] = w[base + 3];
    v[2] = w[base + 35]; v[3] = w[base + 36];
    v[6] = w[base + 37]; v[7] = w[base + 38];
    gate4(v[0], v[1], v[2], v[3], U);   // {1,0}, u1=0
    gate4(v[4], v[5], v[6], v[7], U);   // {1,0}, u1=1
    gate4(v[0], v[2], v[4], v[6], U);   // {2,1}, u0=0
    gate4(v[1], v[3], v[5], v[7], U);   // {2,1}, u0=1
    w[base] = v[0];      w[base + 1] = v[1];
    w[base + 2] = v[4];  w[base + 3] = v[5];
    w[base + 35] = v[2]; w[base + 36] = v[3];
    w[base + 37] = v[6]; w[base + 38] = v[7];
  }
}

// 16-lane expm(A - A^H) in fp64, width-16 shuffles.
__device__ __forceinline__ float2 expm16(const float* __restrict__ Hre,
                                         const float* __restrict__ Him,
                                         int l, int l16) {
  int r = l16 >> 2, c = l16 & 3;
  double tr = (double)Hre[l * 16 + r * 4 + c] - (double)Hre[l * 16 + c * 4 + r];
  double ti = (double)Him[l * 16 + r * 4 + c] + (double)Him[l * 16 + c * 4 + r];
  double a = sqrt(tr * tr + ti * ti);
  a += __shfl_xor(a, 1, 16);
  a += __shfl_xor(a, 2, 16);
  double nrm = fmax(a, __shfl_xor(a, 4, 16));
  nrm = fmax(nrm, __shfl_xor(nrm, 8, 16));
  int s = 0;
  while (nrm > 0.25 && s < 60) { nrm *= 0.5; s++; }
  double sc = ldexp(1.0, -s);
  tr *= sc; ti *= sc;
  double id = (r == c) ? 1.0 : 0.0;
  double er = id, ei = 0.0, pr = id, pi = 0.0;
  for (int k = 1; k <= 16; k++) {
    double qr = 0.0, qi = 0.0;
#pragma unroll
    for (int m = 0; m < 4; m++) {
      double pmr = __shfl(pr, r * 4 + m, 16);
      double pmi = __shfl(pi, r * 4 + m, 16);
      double tmr = __shfl(tr, m * 4 + c, 16);
      double tmi = __shfl(ti, m * 4 + c, 16);
      qr = fma(pmr, tmr, fma(-pmi, tmi, qr));
      qi = fma(pmr, tmi, fma(pmi, tmr, qi));
    }
    double inv = 1.0 / (double)k;
    pr = qr * inv; pi = qi * inv;
    er += pr; ei += pi;
  }
  for (int it = 0; it < s; it++) {
    double qr = 0.0, qi = 0.0;
#pragma unroll
    for (int m = 0; m < 4; m++) {
      double amr = __shfl(er, r * 4 + m, 16);
      double ami = __shfl(ei, r * 4 + m, 16);
      double bmr = __shfl(er, m * 4 + c, 16);
      double bmi = __shfl(ei, m * 4 + c, 16);
      qr = fma(amr, bmr, fma(-ami, bmi, qr));
      qi = fma(amr, bmi, fma(ami, bmr, qi));
    }
    er = qr; ei = qi;
  }
  return make_float2((float)er, (float)ei);
}

// ---------------------------------------------------------------------------
// Kernel B: layer-0 pass 1 + inline expm. Tile = addr bits 0..12 (8192 cplx);
// 11 gates in 4 RTs. Stores permuted into layout F.
// ---------------------------------------------------------------------------
__global__ __launch_bounds__(512, 4) void l0_pass1(const float* __restrict__ pre,
                                                   const float* __restrict__ pim,
                                                   const float* __restrict__ Hre,
                                                   const float* __restrict__ Him,
                                                   float2* __restrict__ Umat,
                                                   float2* __restrict__ state) {
  extern __shared__ float2 tile[];
  __shared__ float2 Ush[16];
  int tid = threadIdx.x;
  int bid = blockIdx.x;
  int b = bid >> 7, hi = bid & 127;   // hi = addr bits 13..19
  size_t base = ((size_t)b << 20) | ((size_t)hi << 13);
  for (int e4 = tid; e4 < 2048; e4 += 512) {
    int e = e4 << 2;
    float4 re = *(const float4*)&pre[base + e];
    float4 im = *(const float4*)&pim[base + e];
    int d = pad(e);
    tile[d] = make_float2(re.x, im.x);
    tile[d + 1] = make_float2(re.y, im.y);
    tile[d + 2] = make_float2(re.z, im.z);
    tile[d + 3] = make_float2(re.w, im.w);
  }
  {
    int wv = tid >> 6, g16 = (tid & 63) >> 4, l16 = tid & 15;
    int layer = (wv == 0) ? g16 : ((wv == 1 && g16 == 0) ? 4 : -1);
    if (layer == 0 || (bid == 0 && layer > 0)) {
      float2 ue = expm16(Hre, Him, layer, l16);
      if (layer == 0) Ush[l16] = ue;
      if (bid == 0) Umat[layer * 16 + l16] = ue;
    }
  }
  __syncthreads();
  float2 U[16];
#pragma unroll
  for (int k = 0; k < 16; k++) U[k] = Ush[k];
  phase4_f<3>(tile, U, 0, 1, 2, 3, 1, 2, 4, 8, tid);            __syncthreads(); // (a1,a0),(a3,a2),(a2,a1)
  phase4_f<3>(tile, U, 4, 5, 6, 7, 16, 32, 64, 128, tid);       __syncthreads(); // (a5,a4),(a7,a6),(a6,a5)
  phase4_f<3>(tile, U, 8, 9, 10, 11, 256, 512, 1024, 2048, tid);__syncthreads(); // (a9,a8),(a11,a10),(a10,a9)
  phase4_f<2>(tile, U, 3, 4, 7, 8, 8, 16, 128, 256, tid);       __syncthreads(); // (a4,a3),(a8,a7)
  // permuted store to F:
  //  le bits (=a2..a12): a2->F2 a3->F3 a4->F8 a5->F12 a6->F10 a7->F13 a8->F9
  //  a9->F14 a10->F11 a11->F15 a12->F4 ; hi (a13..19)->F16,F6,F17,F5,F18,F7,F19
  int hifix = ((hi & 1) << 16) | (((hi >> 1) & 1) << 6) | (((hi >> 2) & 1) << 17)
            | (((hi >> 3) & 1) << 5) | (((hi >> 4) & 1) << 18) | (((hi >> 5) & 1) << 7)
            | (((hi >> 6) & 1) << 19);
  size_t dbase = ((size_t)b << 20) | (unsigned)hifix;
  for (int e4 = tid; e4 < 2048; e4 += 512) {
    int le = e4;
    int d = ((le & 1) << 2) | (((le >> 1) & 1) << 3) | (((le >> 2) & 1) << 8)
          | (((le >> 3) & 1) << 12) | (((le >> 4) & 1) << 10) | (((le >> 5) & 1) << 13)
          | (((le >> 6) & 1) << 9) | (((le >> 7) & 1) << 14) | (((le >> 8) & 1) << 11)
          | (((le >> 9) & 1) << 15) | (((le >> 10) & 1) << 4);
    int src = pad(e4 << 2);
    float2 x0 = tile[src], x1 = tile[src + 1], x2 = tile[src + 2], x3 = tile[src + 3];
    float4* dst = (float4*)&state[dbase + d];
    dst[0] = make_float4(x0.x, x0.y, x1.x, x1.y);
    dst[1] = make_float4(x2.x, x2.y, x3.x, x3.y);
  }
}

// ---------------------------------------------------------------------------
// Kernel C: layer-0 pass 2 in layout F. Tile = F bits {0..7, 15..19} (local
// t0..t7 = F0..7, t8..t12 = F15..19); block-fixed F bits 8..14. In-place.
// Gates (addr->local): E1(13,12)=(t9,t4) E2(15,14)=(t10,t6) E3(17,16)=(t11,t5)
// E4(19,18)=(t12,t7); O1(12,11)=(t4,t8) O2(14,13)=(t6,t9) O3(16,15)=(t5,t10)
// O4(18,17)=(t7,t11); W(0,19)=(t0,t12).
// ---------------------------------------------------------------------------
__global__ __launch_bounds__(512, 4) void l0_pass2(const float2* __restrict__ Umat,
                                                   float2* __restrict__ state) {
  extern __shared__ float2 tile[];
  int tid = threadIdx.x;
  int bid = blockIdx.x;
  int b = bid >> 7, mid = bid & 127;
  size_t base = ((size_t)b << 20) | ((size_t)mid << 8);
  float2 U[16];
#pragma unroll
  for (int k = 0; k < 16; k++) U[k] = Umat[k];
  // load: 32 contiguous runs of 256 cplx (stride 1<<15)
  for (int f = tid; f < 4096; f += 512) {
    int run = f >> 7, idx = f & 127;
    size_t a = base + ((size_t)run << 15) + ((size_t)idx << 1);
    float4 v = *(const float4*)&state[a];
    int d = pad(run * 256 + idx * 2);
    tile[d] = make_float2(v.x, v.y);
    tile[d + 1] = make_float2(v.z, v.w);
  }
  __syncthreads();
  // RT1: E1,E2,O2  (bits {4,6,9,10}; strides t4,t9,t6,t10)
  phase4_f<3>(tile, U, 4, 6, 9, 10, 16, 512, 64, 1024, tid);    __syncthreads();
  // RT2: E3,E4,O4  (bits {5,7,11,12}; strides t5,t11,t7,t12)
  phase4_f<3>(tile, U, 5, 7, 11, 12, 32, 2048, 128, 4096, tid); __syncthreads();
  // RT3: O1,O3    (bits {4,5,8,10}; strides t8,t4,t10,t5)
  phase4_f<2>(tile, U, 4, 5, 8, 10, 256, 16, 1024, 32, tid);    __syncthreads();
  // RT4: wrap W = (pa=t0, pb=t12)
  apply_gate_tile13(tile, U, 0, 12, tid);                       __syncthreads();
  for (int f = tid; f < 4096; f += 512) {
    int run = f >> 7, idx = f & 127;
    size_t a = base + ((size_t)run << 15) + ((size_t)idx << 1);
    int d = pad(run * 256 + idx * 2);
    float2 x0 = tile[d], x1 = tile[d + 1];
    *(float4*)&state[a] = make_float4(x0.x, x0.y, x1.x, x1.y);
  }
}

// ---------------------------------------------------------------------------
// Kernel D: pool0 + layer1 gates + pool1. Contiguous 64KB gather per (b,thi)
// in layout F; LDS w[t*1120 + s*35 + u]; per-block 32x32 partial accumulated
// into rho32 via global f32 atomicAdd (rho32 pre-zeroed by memset).
//  F->tsu: u = F0,F8,F9,F4,F5; s = F2,F10,F11,F6,F7; t = F1,F3,F12.
// ---------------------------------------------------------------------------
__global__ __launch_bounds__(512, 4) void pool_l1(const float2* __restrict__ Umat,
                                                  const float2* __restrict__ state,
                                                  float* __restrict__ rho) {
  extern __shared__ float2 w[];  // 8960 float2
  int tid = threadIdx.x;
  int bid = blockIdx.x;
  int b = bid >> 7, thi = bid & 127;
  size_t base = ((size_t)b << 20) | ((size_t)thi << 13);
  float2 U[16];
#pragma unroll
  for (int k = 0; k < 16; k++) U[k] = Umat[16 + k];
  for (int f = tid; f < 4096; f += 512) {
    int e = f << 1;  // cplx index, even (covers F0 pair = u0 pair)
    float4 v = *(const float4*)&state[base + e];
    int u = (((e >> 8) & 1) << 1) | (((e >> 9) & 1) << 2) | (((e >> 4) & 1) << 3) | (((e >> 5) & 1) << 4);
    int s = ((e >> 2) & 1) | (((e >> 10) & 1) << 1) | (((e >> 11) & 1) << 2)
          | (((e >> 6) & 1) << 3) | (((e >> 7) & 1) << 4);
    int t = ((e >> 1) & 1) | (((e >> 3) & 1) << 1) | (((e >> 12) & 1) << 2);
    int c = t * 1120 + s * 35 + u;
    w[c] = make_float2(v.x, v.y);
    w[c + 1] = make_float2(v.z, v.w);
  }
  __syncthreads();
  // layer-1 gates: i-bit even 2j = u-bit j (stride 2^j); odd 2j+1 = s-bit j (stride 35*2^j)
  phase4_pool<3>(w, U, 3, 4, 3, 4, 8, 280, 16, 560, tid); __syncthreads(); // {7,6},{9,8},{8,7}
  phase4_pool<3>(w, U, 1, 2, 1, 2, 2, 70, 4, 140, tid);   __syncthreads(); // {3,2},{5,4},{4,3}
  pool_p3(w, U, tid);                                     __syncthreads(); // {1,0},{2,1}
  phase4_pool<2>(w, U, 0, 3, 2, 4, 140, 8, 560, 1, tid);  __syncthreads(); // {6,5},{0,9}
  // pool1: rho2[u,v] = sum_{t,s} w[t,s,u]*conj(w[t,s,v]); 4x4 per lane, wave wv = t-row wv
  int wv = tid >> 6, lane = tid & 63;
  int u0 = (lane >> 3) << 2, v0 = (lane & 7) << 2;
  float2 acc[4][4];
#pragma unroll
  for (int i = 0; i < 4; i++)
#pragma unroll
    for (int j = 0; j < 4; j++) acc[i][j] = make_float2(0.f, 0.f);
  {
    int tb = wv * 1120;
#pragma unroll 4
    for (int s = 0; s < 32; s++) {
      int row = tb + s * 35;
      float2 x[4], y[4];
#pragma unroll
      for (int i = 0; i < 4; i++) { x[i] = w[row + u0 + i]; y[i] = w[row + v0 + i]; }
#pragma unroll
      for (int i = 0; i < 4; i++)
#pragma unroll
        for (int j = 0; j < 4; j++) acc[i][j] = cmaddc(acc[i][j], x[i], y[j]);
    }
  }
  __syncthreads();  // w dead; reuse for cross-wave reduce
  if (wv > 0) {
#pragma unroll
    for (int i = 0; i < 4; i++)
#pragma unroll
      for (int j = 0; j < 4; j++)
        w[(wv - 1) * 1024 + (u0 + i) * 32 + (v0 + j)] = acc[i][j];
  }
  __syncthreads();
  if (wv == 0) {
    float* outp = rho + ((size_t)b << 11);  // 2048 floats per batch
#pragma unroll
    for (int i = 0; i < 4; i++)
#pragma unroll
      for (int j = 0; j < 4; j++) {
        float2 a = acc[i][j];
#pragma unroll
        for (int k = 0; k < 7; k++) {
          float2 o = w[k * 1024 + (u0 + i) * 32 + (v0 + j)];
          a.x += o.x; a.y += o.y;
        }
        int idx = ((u0 + i) * 32 + (v0 + j)) * 2;
        atomicAdd(&outp[idx], a.x);
        atomicAdd(&outp[idx + 1], a.y);
      }
  }
}

// ---------------------------------------------------------------------------
// Kernel F: layers 2..4 (32x32 -> 2x2 dm) + measure. One block per batch.
// ---------------------------------------------------------------------------
__global__ __launch_bounds__(256) void finish(const float2* __restrict__ Umat,
                                              const float2* __restrict__ rho32,
                                              float* __restrict__ out) {
  __shared__ float2 rho[1024];
  __shared__ float2 r3s[64];
  __shared__ float2 r4s[16];
  int tid = threadIdx.x;
  int b = blockIdx.x;
  for (int p = tid; p < 1024; p += 256) rho[p] = rho32[(b << 10) + p];
  __syncthreads();

  float2 U[16], Uc[16];
#pragma unroll
  for (int k = 0; k < 16; k++) { U[k] = Umat[32 + k]; Uc[k] = make_float2(U[k].x, -U[k].y); }
  const int gl2[4][2] = {{4,3},{2,1},{3,2},{1,0}};
#pragma unroll
  for (int gi = 0; gi < 4; gi++) {
    int pa = gl2[gi][0], pb = gl2[gi][1];
    int p0 = pa < pb ? pa : pb, p1 = pa < pb ? pb : pa;
    int m0 = (1 << p0) - 1, m1 = (1 << p1) - 1;
    int ia = 1 << pa, ib = 1 << pb;
    {
      int j = tid >> 3, g = tid & 7;
      int idx = ((g & ~m0) << 1) | (g & m0);
      idx = ((idx & ~m1) << 1) | (idx & m1);
      float2 v0 = rho[idx * 32 + j], v1 = rho[(idx | ib) * 32 + j];
      float2 v2 = rho[(idx | ia) * 32 + j], v3 = rho[(idx | ia | ib) * 32 + j];
      gate4(v0, v1, v2, v3, U);
      rho[idx * 32 + j] = v0; rho[(idx | ib) * 32 + j] = v1;
      rho[(idx | ia) * 32 + j] = v2; rho[(idx | ia | ib) * 32 + j] = v3;
    }
    __syncthreads();
    {
      int i = tid >> 3, g = tid & 7;
      int idx = ((g & ~m0) << 1) | (g & m0);
      idx = ((idx & ~m1) << 1) | (idx & m1);
      float2 v0 = rho[i * 32 + idx], v1 = rho[i * 32 + (idx | ib)];
      float2 v2 = rho[i * 32 + (idx | ia)], v3 = rho[i * 32 + (idx | ia | ib)];
      gate4(v0, v1, v2, v3, Uc);
      rho[i * 32 + idx] = v0; rho[i * 32 + (idx | ib)] = v1;
      rho[i * 32 + (idx | ia)] = v2; rho[i * 32 + (idx | ia | ib)] = v3;
    }
    __syncthreads();
  }
  if (tid < 64) {
    int u = tid >> 3, v = tid & 7;
    float2 acc = {0.f, 0.f};
#pragma unroll
    for (int s = 0; s < 4; s++) {
      int iu = ((s >> 1) << 4) | ((u >> 2) << 3) | ((s & 1) << 2) | (((u >> 1) & 1) << 1) | (u & 1);
      int iv = ((s >> 1) << 4) | ((v >> 2) << 3) | ((s & 1) << 2) | (((v >> 1) & 1) << 1) | (v & 1);
      float2 x = rho[iu * 32 + iv];
      acc.x += x.x; acc.y += x.y;
    }
    r3s[u * 8 + v] = acc;
  }
  __syncthreads();

#pragma unroll
  for (int k = 0; k < 16; k++) { U[k] = Umat[48 + k]; Uc[k] = make_float2(U[k].x, -U[k].y); }
  const int gl3[2][2] = {{2,1},{1,0}};
#pragma unroll
  for (int gi = 0; gi < 2; gi++) {
    int pa = gl3[gi][0], pb = gl3[gi][1];
    int p0 = pa < pb ? pa : pb, p1 = pa < pb ? pb : pa;
    int m0 = (1 << p0) - 1, m1 = (1 << p1) - 1;
    int ia = 1 << pa, ib = 1 << pb;
    if (tid < 16) {
      int j = tid >> 1, g = tid & 1;
      int idx = ((g & ~m0) << 1) | (g & m0);
      idx = ((idx & ~m1) << 1) | (idx & m1);
      float2 v0 = r3s[idx * 8 + j], v1 = r3s[(idx | ib) * 8 + j];
      float2 v2 = r3s[(idx | ia) * 8 + j], v3 = r3s[(idx | ia | ib) * 8 + j];
      gate4(v0, v1, v2, v3, U);
      r3s[idx * 8 + j] = v0; r3s[(idx | ib) * 8 + j] = v1;
      r3s[(idx | ia) * 8 + j] = v2; r3s[(idx | ia | ib) * 8 + j] = v3;
    }
    __syncthreads();
    if (tid < 16) {
      int i = tid >> 1, g = tid & 1;
      int idx = ((g & ~m0) << 1) | (g & m0);
      idx = ((idx & ~m1) << 1) | (idx & m1);
      float2 v0 = r3s[i * 8 + idx], v1 = r3s[i * 8 + (idx | ib)];
      float2 v2 = r3s[i * 8 + (idx | ia)], v3 = r3s[i * 8 + (idx | ia | ib)];
      gate4(v0, v1, v2, v3, Uc);
      r3s[i * 8 + idx] = v0; r3s[i * 8 + (idx | ib)] = v1;
      r3s[i * 8 + (idx | ia)] = v2; r3s[i * 8 + (idx | ia | ib)] = v3;
    }
    __syncthreads();
  }
  if (tid < 16) {
    int u = tid >> 2, v = tid & 3;
    float2 acc = {0.f, 0.f};
#pragma unroll
    for (int s = 0; s < 2; s++) {
      float2 x = r3s[((s << 2) | u) * 8 + ((s << 2) | v)];
      acc.x += x.x; acc.y += x.y;
    }
    r4s[u * 4 + v] = acc;
  }
  __syncthreads();

#pragma unroll
  for (int k = 0; k < 16; k++) { U[k] = Umat[64 + k]; Uc[k] = make_float2(U[k].x, -U[k].y); }
  if (tid < 4) {
    int j = tid;
    float2 v0 = r4s[0 * 4 + j], v1 = r4s[1 * 4 + j], v2 = r4s[2 * 4 + j], v3 = r4s[3 * 4 + j];
    gate4(v0, v1, v2, v3, U);
    r4s[0 * 4 + j] = v0; r4s[1 * 4 + j] = v1; r4s[2 * 4 + j] = v2; r4s[3 * 4 + j] = v3;
  }
  __syncthreads();
  if (tid < 4) {
    int i = tid;
    float2 v0 = r4s[i * 4 + 0], v1 = r4s[i * 4 + 1], v2 = r4s[i * 4 + 2], v3 = r4s[i * 4 + 3];
    gate4(v0, v1, v2, v3, Uc);
    r4s[i * 4 + 0] = v0; r4s[i * 4 + 1] = v1; r4s[i * 4 + 2] = v2; r4s[i * 4 + 3] = v3;
  }
  __syncthreads();
  if (tid == 0) out[b] = r4s[0].x + r4s[10].x;
}

// ---------------------------------------------------------------------------
extern "C" void kernel_launch(void* const* d_in, const int* in_sizes, int n_in,
                              void* d_out, int out_size, void* d_ws, size_t ws_size,
                              hipStream_t stream) {
  const float* psi_re = (const float*)d_in[0];
  const float* psi_im = (const float*)d_in[1];
  const float* H_re = (const float*)d_in[2];
  const float* H_im = (const float*)d_in[3];
  float* out = (float*)d_out;

  char* ws = (char*)d_ws;
  float2* Umat = (float2*)ws;                                   // 80 float2
  float2* state = (float2*)(ws + 4096);                         // 32 MB (layout F)
  float* rho32 = (float*)(ws + 4096 + ((size_t)1 << 25));       // 32 KB (atomic acc)

  const size_t LDS_L0 = 8704 * sizeof(float2);    // padded 8192 = 69632 B
  const size_t LDS_POOL = 8960 * sizeof(float2);  // 8*1120 stride-35 rows

  // zero the atomic accumulator early; overlaps with pass1/pass2
  hipMemsetAsync(rho32, 0, 4 * 2048 * sizeof(float), stream);

  hipLaunchKernelGGL(l0_pass1, dim3(512), dim3(512), LDS_L0, stream,
                     psi_re, psi_im, H_re, H_im, Umat, state);
  hipLaunchKernelGGL(l0_pass2, dim3(512), dim3(512), LDS_L0, stream,
                     (const float2*)Umat, state);
  hipLaunchKernelGGL(pool_l1, dim3(512), dim3(512), LDS_POOL, stream,
                     (const float2*)Umat, (const float2*)state, rho32);
  hipLaunchKernelGGL(finish, dim3(4), dim3(256), 0, stream,
                     (const float2*)Umat, (const float2*)rho32, out);
}

// Round 11
// 171.724 us; speedup vs baseline: 1.3134x; 1.3134x over previous
//
#include <hip/hip_runtime.h>
#include <math.h>

// ---------------------------------------------------------------------------
// QCNN forward. Inter-kernel state uses layout F (per batch, 20 bits):
//   F0=a0(u0) F1=a1(t0) F2=a2(s0) F3=a3(t1) F4=a12(u3) F5=a16(u4) F6=a14(s3)
//   F7=a18(s4) F8=a4(u1) F9=a8(u2) F10=a6(s1) F11=a10(s2) F12=a5(t2)
//   F13=a7 F14=a9 F15=a11 F16=a13 F17=a15 F18=a17 F19=a19   (F13..19 = thi)
// pass1: tile=addr bits 0..12, permuted store into F.
// pass2: tile = F bits {0..7,15..19} (in-place safe; gates rescheduled).
// pool:  contiguous 64KB gather per (b,thi); LDS w[t*1120+s*35+u].
// reduce: 2-stage (32-block slice reduce -> finish folds 8 slices).
// Gate digit r = 2*bit(pa)+bit(pb);  qubit q <-> addr bit 19-q.
// ---------------------------------------------------------------------------

__device__ __forceinline__ float2 cmul(float2 a, float2 b) {
  return make_float2(a.x * b.x - a.y * b.y, a.x * b.y + a.y * b.x);
}
__device__ __forceinline__ float2 cmadd(float2 acc, float2 a, float2 b) {
  acc.x = fmaf(a.x, b.x, fmaf(-a.y, b.y, acc.x));
  acc.y = fmaf(a.x, b.y, fmaf(a.y, b.x, acc.y));
  return acc;
}
// acc += a * conj(b)
__device__ __forceinline__ float2 cmaddc(float2 acc, float2 a, float2 b) {
  acc.x = fmaf(a.x, b.x, fmaf(a.y, b.y, acc.x));
  acc.y = fmaf(a.y, b.x, fmaf(-a.x, b.y, acc.y));
  return acc;
}
__device__ __forceinline__ int pad(int e) { return e + (e >> 4); }
__device__ __forceinline__ int ins(int x, int p) {  // insert zero bit at p
  return ((x >> p) << (p + 1)) | (x & ((1 << p) - 1));
}

__device__ __forceinline__ void gate4(float2& v0, float2& v1, float2& v2, float2& v3,
                                      const float2 (&U)[16]) {
  float2 n0 = cmul(U[0], v0);  n0 = cmadd(n0, U[1], v1);  n0 = cmadd(n0, U[2], v2);  n0 = cmadd(n0, U[3], v3);
  float2 n1 = cmul(U[4], v0);  n1 = cmadd(n1, U[5], v1);  n1 = cmadd(n1, U[6], v2);  n1 = cmadd(n1, U[7], v3);
  float2 n2 = cmul(U[8], v0);  n2 = cmadd(n2, U[9], v1);  n2 = cmadd(n2, U[10], v2); n2 = cmadd(n2, U[11], v3);
  float2 n3 = cmul(U[12], v0); n3 = cmadd(n3, U[13], v1); n3 = cmadd(n3, U[14], v2); n3 = cmadd(n3, U[15], v3);
  v0 = n0; v1 = n1; v2 = n2; v3 = n3;
}

// NG gates on a 16-elem register block: (o1,o0), (o3,o2), [+(o2,o1) if NG==3]
template <int NG>
__device__ __forceinline__ void gate16n(float2 (&v)[16], const float2 (&U)[16]) {
#pragma unroll
  for (int g = 0; g < 4; g++)
    gate4(v[g * 4 + 0], v[g * 4 + 1], v[g * 4 + 2], v[g * 4 + 3], U);
#pragma unroll
  for (int lo = 0; lo < 4; lo++)
    gate4(v[lo], v[lo + 4], v[lo + 8], v[lo + 12], U);
  if (NG == 3) {
#pragma unroll
    for (int b3 = 0; b3 < 2; b3++)
#pragma unroll
      for (int b0 = 0; b0 < 2; b0++) {
        int j = b3 * 8 + b0;
        gate4(v[j], v[j + 2], v[j + 4], v[j + 6], U);
      }
  }
}

// single 2-qubit gate (pa,pb bit positions) over padded 2^13 LDS tile (512 thr)
__device__ __forceinline__ void apply_gate_tile13(float2* t, const float2 (&U)[16],
                                                  int pa, int pb, int tid) {
  int p0 = pa < pb ? pa : pb;
  int p1 = pa < pb ? pb : pa;
  int m0 = (1 << p0) - 1, m1 = (1 << p1) - 1;
  int ia = 1 << pa, ib = 1 << pb;
#pragma unroll
  for (int g = tid; g < 2048; g += 512) {
    int idx = ((g & ~m0) << 1) | (g & m0);
    idx = ((idx & ~m1) << 1) | (idx & m1);
    int e0 = pad(idx), e1 = pad(idx | ib), e2 = pad(idx | ia), e3 = pad(idx | ia | ib);
    float2 v0 = t[e0], v1 = t[e1], v2 = t[e2], v3 = t[e3];
    gate4(v0, v1, v2, v3, U);
    t[e0] = v0; t[e1] = v1; t[e2] = v2; t[e3] = v3;
  }
}

// register phase over a padded 2^13 tile. q0<q1<q2<q3 = sorted bit positions;
// o0..o3 = gate-ordered strides (gates (o1,o0),(o3,o2)[,(o2,o1)]).
// 512 threads -> exactly one 16-group per thread.
template <int NG>
__device__ __forceinline__ void phase4_f(float2* t, const float2 (&U)[16],
                                         int q0, int q1, int q2, int q3,
                                         int o0, int o1, int o2, int o3, int tid) {
  int idx = ins(ins(ins(ins(tid, q0), q1), q2), q3);
  float2 v[16];
#pragma unroll
  for (int j = 0; j < 16; j++) {
    int off = ((j & 1) ? o0 : 0) + ((j & 2) ? o1 : 0) + ((j & 4) ? o2 : 0) + ((j & 8) ? o3 : 0);
    v[j] = t[pad(idx + off)];
  }
  gate16n<NG>(v, U);
#pragma unroll
  for (int j = 0; j < 16; j++) {
    int off = ((j & 1) ? o0 : 0) + ((j & 2) ? o1 : 0) + ((j & 4) ? o2 : 0) + ((j & 8) ? o3 : 0);
    t[pad(idx + off)] = v[j];
  }
}

// pool register phase (stride-35 LDS): removes u-bits {a_lo<a_hi},
// s-bits {c_lo<c_hi}; o0..o3 = gate-ordered flat strides
template <int NG>
__device__ __forceinline__ void phase4_pool(float2* w, const float2 (&U)[16],
                                            int a_lo, int a_hi, int c_lo, int c_hi,
                                            int o0, int o1, int o2, int o3, int tid) {
  int uu = tid & 7, ss = (tid >> 3) & 7, t_lo = tid >> 6;
  int u = ins(ins(uu, a_lo), a_hi);
  int s = ins(ins(ss, c_lo), c_hi);
  int base = t_lo * 1120 + s * 35 + u;
  float2 v[16];
#pragma unroll
  for (int j = 0; j < 16; j++) {
    int off = ((j & 1) ? o0 : 0) + ((j & 2) ? o1 : 0) + ((j & 4) ? o2 : 0) + ((j & 8) ? o3 : 0);
    v[j] = w[base + off];
  }
  gate16n<NG>(v, U);
#pragma unroll
  for (int j = 0; j < 16; j++) {
    int off = ((j & 1) ? o0 : 0) + ((j & 2) ? o1 : 0) + ((j & 4) ? o2 : 0) + ((j & 8) ? o3 : 0);
    w[base + off] = v[j];
  }
}

// pool P3: gates {1,0} then {2,1} on locals [o0=1(u0), o1=35(s0), o2=2(u1)]
__device__ __forceinline__ void pool_p3(float2* w, const float2 (&U)[16], int tid) {
#pragma unroll
  for (int it = 0; it < 2; it++) {
    int h = tid + it * 512;
    int uu = h & 7, ss = (h >> 3) & 15, t_lo = h >> 7;
    int base = t_lo * 1120 + (ss << 1) * 35 + (uu << 2);
    float2 v[8];
    v[0] = w[base];      v[1] = w[base + 1];
    v[4] = w[base + 2];  v[5] = w[base + 3];
    v[2] = w[base + 35]; v[3] = w[base + 36];
    v[6] = w[base + 37]; v[7] = w[base + 38];
    gate4(v[0], v[1], v[2], v[3], U);   // {1,0}, u1=0
    gate4(v[4], v[5], v[6], v[7], U);   // {1,0}, u1=1
    gate4(v[0], v[2], v[4], v[6], U);   // {2,1}, u0=0
    gate4(v[1], v[3], v[5], v[7], U);   // {2,1}, u0=1
    w[base] = v[0];      w[base + 1] = v[1];
    w[base + 2] = v[4];  w[base + 3] = v[5];
    w[base + 35] = v[2]; w[base + 36] = v[3];
    w[base + 37] = v[6]; w[base + 38] = v[7];
  }
}

// 16-lane expm(A - A^H) in fp64, width-16 shuffles.
__device__ __forceinline__ float2 expm16(const float* __restrict__ Hre,
                                         const float* __restrict__ Him,
                                         int l, int l16) {
  int r = l16 >> 2, c = l16 & 3;
  double tr = (double)Hre[l * 16 + r * 4 + c] - (double)Hre[l * 16 + c * 4 + r];
  double ti = (double)Him[l * 16 + r * 4 + c] + (double)Him[l * 16 + c * 4 + r];
  double a = sqrt(tr * tr + ti * ti);
  a += __shfl_xor(a, 1, 16);
  a += __shfl_xor(a, 2, 16);
  double nrm = fmax(a, __shfl_xor(a, 4, 16));
  nrm = fmax(nrm, __shfl_xor(nrm, 8, 16));
  int s = 0;
  while (nrm > 0.25 && s < 60) { nrm *= 0.5; s++; }
  double sc = ldexp(1.0, -s);
  tr *= sc; ti *= sc;
  double id = (r == c) ? 1.0 : 0.0;
  double er = id, ei = 0.0, pr = id, pi = 0.0;
  for (int k = 1; k <= 16; k++) {
    double qr = 0.0, qi = 0.0;
#pragma unroll
    for (int m = 0; m < 4; m++) {
      double pmr = __shfl(pr, r * 4 + m, 16);
      double pmi = __shfl(pi, r * 4 + m, 16);
      double tmr = __shfl(tr, m * 4 + c, 16);
      double tmi = __shfl(ti, m * 4 + c, 16);
      qr = fma(pmr, tmr, fma(-pmi, tmi, qr));
      qi = fma(pmr, tmi, fma(pmi, tmr, qi));
    }
    double inv = 1.0 / (double)k;
    pr = qr * inv; pi = qi * inv;
    er += pr; ei += pi;
  }
  for (int it = 0; it < s; it++) {
    double qr = 0.0, qi = 0.0;
#pragma unroll
    for (int m = 0; m < 4; m++) {
      double amr = __shfl(er, r * 4 + m, 16);
      double ami = __shfl(ei, r * 4 + m, 16);
      double bmr = __shfl(er, m * 4 + c, 16);
      double bmi = __shfl(ei, m * 4 + c, 16);
      qr = fma(amr, bmr, fma(-ami, bmi, qr));
      qi = fma(amr, bmi, fma(ami, bmr, qi));
    }
    er = qr; ei = qi;
  }
  return make_float2((float)er, (float)ei);
}

// ---------------------------------------------------------------------------
// Kernel B: layer-0 pass 1 + inline expm. Tile = addr bits 0..12 (8192 cplx);
// 11 gates in 4 RTs. Stores permuted into layout F.
// ---------------------------------------------------------------------------
__global__ __launch_bounds__(512, 4) void l0_pass1(const float* __restrict__ pre,
                                                   const float* __restrict__ pim,
                                                   const float* __restrict__ Hre,
                                                   const float* __restrict__ Him,
                                                   float2* __restrict__ Umat,
                                                   float2* __restrict__ state) {
  extern __shared__ float2 tile[];
  __shared__ float2 Ush[16];
  int tid = threadIdx.x;
  int bid = blockIdx.x;
  int b = bid >> 7, hi = bid & 127;   // hi = addr bits 13..19
  size_t base = ((size_t)b << 20) | ((size_t)hi << 13);
  for (int e4 = tid; e4 < 2048; e4 += 512) {
    int e = e4 << 2;
    float4 re = *(const float4*)&pre[base + e];
    float4 im = *(const float4*)&pim[base + e];
    int d = pad(e);
    tile[d] = make_float2(re.x, im.x);
    tile[d + 1] = make_float2(re.y, im.y);
    tile[d + 2] = make_float2(re.z, im.z);
    tile[d + 3] = make_float2(re.w, im.w);
  }
  {
    int wv = tid >> 6, g16 = (tid & 63) >> 4, l16 = tid & 15;
    int layer = (wv == 0) ? g16 : ((wv == 1 && g16 == 0) ? 4 : -1);
    if (layer == 0 || (bid == 0 && layer > 0)) {
      float2 ue = expm16(Hre, Him, layer, l16);
      if (layer == 0) Ush[l16] = ue;
      if (bid == 0) Umat[layer * 16 + l16] = ue;
    }
  }
  __syncthreads();
  float2 U[16];
#pragma unroll
  for (int k = 0; k < 16; k++) U[k] = Ush[k];
  phase4_f<3>(tile, U, 0, 1, 2, 3, 1, 2, 4, 8, tid);            __syncthreads(); // (a1,a0),(a3,a2),(a2,a1)
  phase4_f<3>(tile, U, 4, 5, 6, 7, 16, 32, 64, 128, tid);       __syncthreads(); // (a5,a4),(a7,a6),(a6,a5)
  phase4_f<3>(tile, U, 8, 9, 10, 11, 256, 512, 1024, 2048, tid);__syncthreads(); // (a9,a8),(a11,a10),(a10,a9)
  phase4_f<2>(tile, U, 3, 4, 7, 8, 8, 16, 128, 256, tid);       __syncthreads(); // (a4,a3),(a8,a7)
  // permuted store to F:
  //  le bits (=a2..a12): a2->F2 a3->F3 a4->F8 a5->F12 a6->F10 a7->F13 a8->F9
  //  a9->F14 a10->F11 a11->F15 a12->F4 ; hi (a13..19)->F16,F6,F17,F5,F18,F7,F19
  int hifix = ((hi & 1) << 16) | (((hi >> 1) & 1) << 6) | (((hi >> 2) & 1) << 17)
            | (((hi >> 3) & 1) << 5) | (((hi >> 4) & 1) << 18) | (((hi >> 5) & 1) << 7)
            | (((hi >> 6) & 1) << 19);
  size_t dbase = ((size_t)b << 20) | (unsigned)hifix;
  for (int e4 = tid; e4 < 2048; e4 += 512) {
    int le = e4;
    int d = ((le & 1) << 2) | (((le >> 1) & 1) << 3) | (((le >> 2) & 1) << 8)
          | (((le >> 3) & 1) << 12) | (((le >> 4) & 1) << 10) | (((le >> 5) & 1) << 13)
          | (((le >> 6) & 1) << 9) | (((le >> 7) & 1) << 14) | (((le >> 8) & 1) << 11)
          | (((le >> 9) & 1) << 15) | (((le >> 10) & 1) << 4);
    int src = pad(e4 << 2);
    float2 x0 = tile[src], x1 = tile[src + 1], x2 = tile[src + 2], x3 = tile[src + 3];
    float4* dst = (float4*)&state[dbase + d];
    dst[0] = make_float4(x0.x, x0.y, x1.x, x1.y);
    dst[1] = make_float4(x2.x, x2.y, x3.x, x3.y);
  }
}

// ---------------------------------------------------------------------------
// Kernel C: layer-0 pass 2 in layout F. Tile = F bits {0..7, 15..19} (local
// t0..t7 = F0..7, t8..t12 = F15..19); block-fixed F bits 8..14. In-place.
// Gates (addr->local): E1(13,12)=(t9,t4) E2(15,14)=(t10,t6) E3(17,16)=(t11,t5)
// E4(19,18)=(t12,t7); O1(12,11)=(t4,t8) O2(14,13)=(t6,t9) O3(16,15)=(t5,t10)
// O4(18,17)=(t7,t11); W(0,19)=(t0,t12).
// ---------------------------------------------------------------------------
__global__ __launch_bounds__(512, 4) void l0_pass2(const float2* __restrict__ Umat,
                                                   float2* __restrict__ state) {
  extern __shared__ float2 tile[];
  int tid = threadIdx.x;
  int bid = blockIdx.x;
  int b = bid >> 7, mid = bid & 127;
  size_t base = ((size_t)b << 20) | ((size_t)mid << 8);
  float2 U[16];
#pragma unroll
  for (int k = 0; k < 16; k++) U[k] = Umat[k];
  // load: 32 contiguous runs of 256 cplx (stride 1<<15)
  for (int f = tid; f < 4096; f += 512) {
    int run = f >> 7, idx = f & 127;
    size_t a = base + ((size_t)run << 15) + ((size_t)idx << 1);
    float4 v = *(const float4*)&state[a];
    int d = pad(run * 256 + idx * 2);
    tile[d] = make_float2(v.x, v.y);
    tile[d + 1] = make_float2(v.z, v.w);
  }
  __syncthreads();
  // RT1: E1,E2,O2  (bits {4,6,9,10}; strides t4,t9,t6,t10)
  phase4_f<3>(tile, U, 4, 6, 9, 10, 16, 512, 64, 1024, tid);    __syncthreads();
  // RT2: E3,E4,O4  (bits {5,7,11,12}; strides t5,t11,t7,t12)
  phase4_f<3>(tile, U, 5, 7, 11, 12, 32, 2048, 128, 4096, tid); __syncthreads();
  // RT3: O1,O3    (bits {4,5,8,10}; strides t8,t4,t10,t5)
  phase4_f<2>(tile, U, 4, 5, 8, 10, 256, 16, 1024, 32, tid);    __syncthreads();
  // RT4: wrap W = (pa=t0, pb=t12)
  apply_gate_tile13(tile, U, 0, 12, tid);                       __syncthreads();
  for (int f = tid; f < 4096; f += 512) {
    int run = f >> 7, idx = f & 127;
    size_t a = base + ((size_t)run << 15) + ((size_t)idx << 1);
    int d = pad(run * 256 + idx * 2);
    float2 x0 = tile[d], x1 = tile[d + 1];
    *(float4*)&state[a] = make_float4(x0.x, x0.y, x1.x, x1.y);
  }
}

// ---------------------------------------------------------------------------
// Kernel D: pool0 + layer1 gates + pool1 partials. Contiguous 64KB gather per
// (b,thi) in layout F; LDS w[t*1120 + s*35 + u].
//  F->tsu: u = F0,F8,F9,F4,F5; s = F2,F10,F11,F6,F7; t = F1,F3,F12.
// ---------------------------------------------------------------------------
__global__ __launch_bounds__(512, 4) void pool_l1(const float2* __restrict__ Umat,
                                                  const float2* __restrict__ state,
                                                  float2* __restrict__ partial) {
  extern __shared__ float2 w[];  // 8960 float2
  int tid = threadIdx.x;
  int bid = blockIdx.x;
  int b = bid >> 7, thi = bid & 127;
  size_t base = ((size_t)b << 20) | ((size_t)thi << 13);
  float2 U[16];
#pragma unroll
  for (int k = 0; k < 16; k++) U[k] = Umat[16 + k];
  for (int f = tid; f < 4096; f += 512) {
    int e = f << 1;  // cplx index, even (covers F0 pair = u0 pair)
    float4 v = *(const float4*)&state[base + e];
    int u = (((e >> 8) & 1) << 1) | (((e >> 9) & 1) << 2) | (((e >> 4) & 1) << 3) | (((e >> 5) & 1) << 4);
    int s = ((e >> 2) & 1) | (((e >> 10) & 1) << 1) | (((e >> 11) & 1) << 2)
          | (((e >> 6) & 1) << 3) | (((e >> 7) & 1) << 4);
    int t = ((e >> 1) & 1) | (((e >> 3) & 1) << 1) | (((e >> 12) & 1) << 2);
    int c = t * 1120 + s * 35 + u;
    w[c] = make_float2(v.x, v.y);
    w[c + 1] = make_float2(v.z, v.w);
  }
  __syncthreads();
  // layer-1 gates: i-bit even 2j = u-bit j (stride 2^j); odd 2j+1 = s-bit j (stride 35*2^j)
  phase4_pool<3>(w, U, 3, 4, 3, 4, 8, 280, 16, 560, tid); __syncthreads(); // {7,6},{9,8},{8,7}
  phase4_pool<3>(w, U, 1, 2, 1, 2, 2, 70, 4, 140, tid);   __syncthreads(); // {3,2},{5,4},{4,3}
  pool_p3(w, U, tid);                                     __syncthreads(); // {1,0},{2,1}
  phase4_pool<2>(w, U, 0, 3, 2, 4, 140, 8, 560, 1, tid);  __syncthreads(); // {6,5},{0,9}
  // pool1: rho2[u,v] = sum_{t,s} w[t,s,u]*conj(w[t,s,v]); 4x4 per lane, wave wv = t-row wv
  int wv = tid >> 6, lane = tid & 63;
  int u0 = (lane >> 3) << 2, v0 = (lane & 7) << 2;
  float2 acc[4][4];
#pragma unroll
  for (int i = 0; i < 4; i++)
#pragma unroll
    for (int j = 0; j < 4; j++) acc[i][j] = make_float2(0.f, 0.f);
  {
    int tb = wv * 1120;
#pragma unroll 4
    for (int s = 0; s < 32; s++) {
      int row = tb + s * 35;
      float2 x[4], y[4];
#pragma unroll
      for (int i = 0; i < 4; i++) { x[i] = w[row + u0 + i]; y[i] = w[row + v0 + i]; }
#pragma unroll
      for (int i = 0; i < 4; i++)
#pragma unroll
        for (int j = 0; j < 4; j++) acc[i][j] = cmaddc(acc[i][j], x[i], y[j]);
    }
  }
  __syncthreads();  // w dead; reuse for cross-wave reduce
  if (wv > 0) {
#pragma unroll
    for (int i = 0; i < 4; i++)
#pragma unroll
      for (int j = 0; j < 4; j++)
        w[(wv - 1) * 1024 + (u0 + i) * 32 + (v0 + j)] = acc[i][j];
  }
  __syncthreads();
  if (wv == 0) {
    float2* outp = partial + ((size_t)bid << 10);
#pragma unroll
    for (int i = 0; i < 4; i++)
#pragma unroll
      for (int j = 0; j < 4; j++) {
        float2 a = acc[i][j];
#pragma unroll
        for (int k = 0; k < 7; k++) {
          float2 o = w[k * 1024 + (u0 + i) * 32 + (v0 + j)];
          a.x += o.x; a.y += o.y;
        }
        outp[(u0 + i) * 32 + (v0 + j)] = a;
      }
  }
}

// ---------------------------------------------------------------------------
// Kernel E: stage-1 reduce. 32 blocks = (batch b, slice q of 16 tiles);
// inter[(b*8+q)*512 + o] = sum of the slice. No shared addresses -> no atomics.
// ---------------------------------------------------------------------------
__global__ __launch_bounds__(256) void reduce_partials(const float4* __restrict__ partial,
                                                       float4* __restrict__ inter) {
  int blk = blockIdx.x;           // 0..31
  int b = blk >> 3, q = blk & 7;  // 8 slices per batch
  int tid = threadIdx.x;
  for (int o = tid; o < 512; o += 256) {
    float4 acc = make_float4(0.f, 0.f, 0.f, 0.f);
#pragma unroll 4
    for (int h = 0; h < 16; h++) {
      int tile = (b * 128) + (q * 16) + h;
      float4 v = partial[(size_t)tile * 512 + o];
      acc.x += v.x; acc.y += v.y; acc.z += v.z; acc.w += v.w;
    }
    inter[(size_t)blk * 512 + o] = acc;
  }
}

// ---------------------------------------------------------------------------
// Kernel F: fold 8 slices + layers 2..4 (32x32 -> 2x2 dm) + measure.
// One block per batch.
// ---------------------------------------------------------------------------
__global__ __launch_bounds__(256) void finish(const float2* __restrict__ Umat,
                                              const float4* __restrict__ inter,
                                              float* __restrict__ out) {
  __shared__ float2 rho[1024];
  __shared__ float2 r3s[64];
  __shared__ float2 r4s[16];
  int tid = threadIdx.x;
  int b = blockIdx.x;
  float4* rf = (float4*)rho;
  for (int f = tid; f < 512; f += 256) {
    float4 acc = make_float4(0.f, 0.f, 0.f, 0.f);
#pragma unroll
    for (int q = 0; q < 8; q++) {
      float4 v = inter[(size_t)(b * 8 + q) * 512 + f];
      acc.x += v.x; acc.y += v.y; acc.z += v.z; acc.w += v.w;
    }
    rf[f] = acc;
  }
  __syncthreads();

  float2 U[16], Uc[16];
#pragma unroll
  for (int k = 0; k < 16; k++) { U[k] = Umat[32 + k]; Uc[k] = make_float2(U[k].x, -U[k].y); }
  const int gl2[4][2] = {{4,3},{2,1},{3,2},{1,0}};
#pragma unroll
  for (int gi = 0; gi < 4; gi++) {
    int pa = gl2[gi][0], pb = gl2[gi][1];
    int p0 = pa < pb ? pa : pb, p1 = pa < pb ? pb : pa;
    int m0 = (1 << p0) - 1, m1 = (1 << p1) - 1;
    int ia = 1 << pa, ib = 1 << pb;
    {
      int j = tid >> 3, g = tid & 7;
      int idx = ((g & ~m0) << 1) | (g & m0);
      idx = ((idx & ~m1) << 1) | (idx & m1);
      float2 v0 = rho[idx * 32 + j], v1 = rho[(idx | ib) * 32 + j];
      float2 v2 = rho[(idx | ia) * 32 + j], v3 = rho[(idx | ia | ib) * 32 + j];
      gate4(v0, v1, v2, v3, U);
      rho[idx * 32 + j] = v0; rho[(idx | ib) * 32 + j] = v1;
      rho[(idx | ia) * 32 + j] = v2; rho[(idx | ia | ib) * 32 + j] = v3;
    }
    __syncthreads();
    {
      int i = tid >> 3, g = tid & 7;
      int idx = ((g & ~m0) << 1) | (g & m0);
      idx = ((idx & ~m1) << 1) | (idx & m1);
      float2 v0 = rho[i * 32 + idx], v1 = rho[i * 32 + (idx | ib)];
      float2 v2 = rho[i * 32 + (idx | ia)], v3 = rho[i * 32 + (idx | ia | ib)];
      gate4(v0, v1, v2, v3, Uc);
      rho[i * 32 + idx] = v0; rho[i * 32 + (idx | ib)] = v1;
      rho[i * 32 + (idx | ia)] = v2; rho[i * 32 + (idx | ia | ib)] = v3;
    }
    __syncthreads();
  }
  if (tid < 64) {
    int u = tid >> 3, v = tid & 7;
    float2 acc = {0.f, 0.f};
#pragma unroll
    for (int s = 0; s < 4; s++) {
      int iu = ((s >> 1) << 4) | ((u >> 2) << 3) | ((s & 1) << 2) | (((u >> 1) & 1) << 1) | (u & 1);
      int iv = ((s >> 1) << 4) | ((v >> 2) << 3) | ((s & 1) << 2) | (((v >> 1) & 1) << 1) | (v & 1);
      float2 x = rho[iu * 32 + iv];
      acc.x += x.x; acc.y += x.y;
    }
    r3s[u * 8 + v] = acc;
  }
  __syncthreads();

#pragma unroll
  for (int k = 0; k < 16; k++) { U[k] = Umat[48 + k]; Uc[k] = make_float2(U[k].x, -U[k].y); }
  const int gl3[2][2] = {{2,1},{1,0}};
#pragma unroll
  for (int gi = 0; gi < 2; gi++) {
    int pa = gl3[gi][0], pb = gl3[gi][1];
    int p0 = pa < pb ? pa : pb, p1 = pa < pb ? pb : pa;
    int m0 = (1 << p0) - 1, m1 = (1 << p1) - 1;
    int ia = 1 << pa, ib = 1 << pb;
    if (tid < 16) {
      int j = tid >> 1, g = tid & 1;
      int idx = ((g & ~m0) << 1) | (g & m0);
      idx = ((idx & ~m1) << 1) | (idx & m1);
      float2 v0 = r3s[idx * 8 + j], v1 = r3s[(idx | ib) * 8 + j];
      float2 v2 = r3s[(idx | ia) * 8 + j], v3 = r3s[(idx | ia | ib) * 8 + j];
      gate4(v0, v1, v2, v3, U);
      r3s[idx * 8 + j] = v0; r3s[(idx | ib) * 8 + j] = v1;
      r3s[(idx | ia) * 8 + j] = v2; r3s[(idx | ia | ib) * 8 + j] = v3;
    }
    __syncthreads();
    if (tid < 16) {
      int i = tid >> 1, g = tid & 1;
      int idx = ((g & ~m0) << 1) | (g & m0);
      idx = ((idx & ~m1) << 1) | (idx & m1);
      float2 v0 = r3s[i * 8 + idx], v1 = r3s[i * 8 + (idx | ib)];
      float2 v2 = r3s[i * 8 + (idx | ia)], v3 = r3s[i * 8 + (idx | ia | ib)];
      gate4(v0, v1, v2, v3, Uc);
      r3s[i * 8 + idx] = v0; r3s[i * 8 + (idx | ib)] = v1;
      r3s[i * 8 + (idx | ia)] = v2; r3s[i * 8 + (idx | ia | ib)] = v3;
    }
    __syncthreads();
  }
  if (tid < 16) {
    int u = tid >> 2, v = tid & 3;
    float2 acc = {0.f, 0.f};
#pragma unroll
    for (int s = 0; s < 2; s++) {
      float2 x = r3s[((s << 2) | u) * 8 + ((s << 2) | v)];
      acc.x += x.x; acc.y += x.y;
    }
    r4s[u * 4 + v] = acc;
  }
  __syncthreads();

#pragma unroll
  for (int k = 0; k < 16; k++) { U[k] = Umat[64 + k]; Uc[k] = make_float2(U[k].x, -U[k].y); }
  if (tid < 4) {
    int j = tid;
    float2 v0 = r4s[0 * 4 + j], v1 = r4s[1 * 4 + j], v2 = r4s[2 * 4 + j], v3 = r4s[3 * 4 + j];
    gate4(v0, v1, v2, v3, U);
    r4s[0 * 4 + j] = v0; r4s[1 * 4 + j] = v1; r4s[2 * 4 + j] = v2; r4s[3 * 4 + j] = v3;
  }
  __syncthreads();
  if (tid < 4) {
    int i = tid;
    float2 v0 = r4s[i * 4 + 0], v1 = r4s[i * 4 + 1], v2 = r4s[i * 4 + 2], v3 = r4s[i * 4 + 3];
    gate4(v0, v1, v2, v3, Uc);
    r4s[i * 4 + 0] = v0; r4s[i * 4 + 1] = v1; r4s[i * 4 + 2] = v2; r4s[i * 4 + 3] = v3;
  }
  __syncthreads();
  if (tid == 0) out[b] = r4s[0].x + r4s[10].x;
}

// ---------------------------------------------------------------------------
extern "C" void kernel_launch(void* const* d_in, const int* in_sizes, int n_in,
                              void* d_out, int out_size, void* d_ws, size_t ws_size,
                              hipStream_t stream) {
  const float* psi_re = (const float*)d_in[0];
  const float* psi_im = (const float*)d_in[1];
  const float* H_re = (const float*)d_in[2];
  const float* H_im = (const float*)d_in[3];
  float* out = (float*)d_out;

  char* ws = (char*)d_ws;
  float2* Umat = (float2*)ws;                                   // 80 float2
  float2* state = (float2*)(ws + 4096);                         // 32 MB (layout F)
  float* partial = (float*)(ws + 4096 + ((size_t)1 << 25));     // 4 MB
  float* inter = (float*)(ws + 4096 + ((size_t)1 << 25) + ((size_t)1 << 22));  // 256 KB

  const size_t LDS_L0 = 8704 * sizeof(float2);    // padded 8192 = 69632 B
  const size_t LDS_POOL = 8960 * sizeof(float2);  // 8*1120 stride-35 rows

  hipLaunchKernelGGL(l0_pass1, dim3(512), dim3(512), LDS_L0, stream,
                     psi_re, psi_im, H_re, H_im, Umat, state);
  hipLaunchKernelGGL(l0_pass2, dim3(512), dim3(512), LDS_L0, stream,
                     (const float2*)Umat, state);
  hipLaunchKernelGGL(pool_l1, dim3(512), dim3(512), LDS_POOL, stream,
                     (const float2*)Umat, (const float2*)state, (float2*)partial);
  hipLaunchKernelGGL(reduce_partials, dim3(32), dim3(256), 0, stream,
                     (const float4*)partial, (float4*)inter);
  hipLaunchKernelGGL(finish, dim3(4), dim3(256), 0, stream,
                     (const float2*)Umat, (const float4*)inter, out);
}